// Round 7
// baseline (462.447 us; speedup 1.0000x reference)
//
#include <hip/hip_runtime.h>
#include <hip/hip_bf16.h>
#include <hip/hip_cooperative_groups.h>
#include <stdint.h>

namespace cg = cooperative_groups;

// GroupQuerySelfAttention: B=2, S=2048, D=768, NH=12, GH=4, HD=64, REP=3
// SCALE=0.125, MASK_FILL=-1e-9 => masked weight = expf(-1e-9f) == 1.0f.
// Inputs fp32, output fp32 (established r1/r2).
//
// R7: ONE cooperative kernel (512 blocks x 256), phases separated by
// grid.sync(); phase bodies are the r5 kernels verbatim (r6 proved direct-
// global MFMA operands are latency-bound; LDS staging wins). Attn jobs are
// snake-balanced over blocks. Eliminates 5 inter-kernel launch/ramp gaps.
//
// MFMA 16x16x32_bf16 layouts (HW-verified):
//   A[m=lane&15][k=quad*8+j]  B[n=lane&15][k=quad*8+j]  C col=lane&15,row=quad*4+reg

typedef unsigned short ushort_t;
typedef short bf16x8 __attribute__((ext_vector_type(8)));
typedef float f32x4 __attribute__((ext_vector_type(4)));

#define MFMA(a, b, c) __builtin_amdgcn_mfma_f32_16x16x32_bf16((a), (b), (c), 0, 0, 0)

__device__ __forceinline__ ushort_t f2bf(float f) {   // RNE fp32->bf16 (finite)
    union { float f; unsigned u; } v; v.f = f;
    const unsigned r = v.u + 0x7FFFu + ((v.u >> 16) & 1u);
    return (ushort_t)(r >> 16);
}
__device__ __forceinline__ unsigned pk2(float a, float b) {  // packed RNE pair
    __hip_bfloat162 h = __float22bfloat162_rn(make_float2(a, b));
    unsigned u; __builtin_memcpy(&u, &h, 4); return u;
}
__device__ __forceinline__ float bflo(unsigned u) {
    union { unsigned u; float f; } v; v.u = u << 16; return v.f;
}
__device__ __forceinline__ float bfhi(unsigned u) {
    union { unsigned u; float f; } v; v.u = u & 0xFFFF0000u; return v.f;
}

struct Params {
    const float *x, *Wq, *bq, *Wk, *bk, *Wv, *bv, *Wo, *bo;
    float* out;
    ushort_t *xb, *WqT, *WkT, *WvT, *WoT, *Qb, *Kb, *Vtb;
    float* Vsuf;
    ushort_t *aT_hi, *aT_lo;
};

// ---------------------------------------------------------------------------
// P0a: x fp32 -> bf16. 64 jobs, each 64 rows x 768 cols (49152 elems).
__device__ __forceinline__ void prep_x_job(int jx, const Params& p) {
    const int tid = threadIdx.x;
    const int base = jx * 49152;
    #pragma unroll 4
    for (int it = 0; it < 48; ++it) {
        const int i = base + it * 1024 + tid * 4;
        const float4 v = *(const float4*)(p.x + i);
        uint2 pk; pk.x = pk2(v.x, v.y); pk.y = pk2(v.z, v.w);
        *(uint2*)(p.xb + i) = pk;
    }
}

// ---------------------------------------------------------------------------
// P0b: weight transpose+cast: [768 k][N n] fp32 -> [N n][768 k] bf16.
// 384 jobs: 144 Wq, 48 Wk, 48 Wv, 144 Wo.
__device__ __forceinline__ void prep_w_job(int jw, const Params& p, uint8_t* sm) {
    const float* src; ushort_t* dst; int N, kt, nt;
    if (jw < 144)      { src = p.Wq; dst = p.WqT; N = 768; kt = jw / 12;        nt = jw % 12; }
    else if (jw < 192) { src = p.Wk; dst = p.WkT; N = 256; kt = (jw - 144) / 4; nt = (jw - 144) % 4; }
    else if (jw < 240) { src = p.Wv; dst = p.WvT; N = 256; kt = (jw - 192) / 4; nt = (jw - 192) % 4; }
    else               { src = p.Wo; dst = p.WoT; N = 768; kt = (jw - 240) / 12; nt = (jw - 240) % 12; }
    const int k0 = kt * 64, n0 = nt * 64;

    float (*Ts)[65] = (float(*)[65])sm;
    const int tid = threadIdx.x;
    const int r = tid >> 2, cb = (tid & 3) * 16;
    #pragma unroll
    for (int jj = 0; jj < 4; ++jj) {
        const float4 v = *(const float4*)(src + (k0 + r) * N + n0 + cb + jj * 4);
        Ts[cb + jj * 4 + 0][r] = v.x; Ts[cb + jj * 4 + 1][r] = v.y;
        Ts[cb + jj * 4 + 2][r] = v.z; Ts[cb + jj * 4 + 3][r] = v.w;
    }
    __syncthreads();
    const int n = tid >> 2, kc = (tid & 3) * 16;
    unsigned hbuf[16];
    #pragma unroll
    for (int j = 0; j < 16; ++j) hbuf[j] = f2bf(Ts[n][kc + j]);
    uint4 p0, p1;
    p0.x = hbuf[0] | (hbuf[1] << 16);   p0.y = hbuf[2] | (hbuf[3] << 16);
    p0.z = hbuf[4] | (hbuf[5] << 16);   p0.w = hbuf[6] | (hbuf[7] << 16);
    p1.x = hbuf[8] | (hbuf[9] << 16);   p1.y = hbuf[10] | (hbuf[11] << 16);
    p1.z = hbuf[12] | (hbuf[13] << 16); p1.w = hbuf[14] | (hbuf[15] << 16);
    *(uint4*)(dst + (n0 + n) * 768 + k0 + kc) = p0;
    *(uint4*)(dst + (n0 + n) * 768 + k0 + kc + 8) = p1;
}

// ---------------------------------------------------------------------------
// P1: QKV projection, 128-row tiles (r5 body). 640 jobs (20 ct x 32 rt).
__device__ __forceinline__ void qkv_job(int jq, const Params& p, uint8_t* sm) {
    const int ct = jq / 32, rt = jq % 32;
    const int r0 = rt * 128;
    const ushort_t* WT; const float* bias; int head, kind;   // 0=Q,1=K,2=V
    if (ct < 12)      { WT = p.WqT; bias = p.bq; head = ct;      kind = 0; }
    else if (ct < 16) { WT = p.WkT; bias = p.bk; head = ct - 12; kind = 1; }
    else              { WT = p.WvT; bias = p.bv; head = ct - 16; kind = 2; }
    const int n0 = head * 64;

    uint4* Xs = (uint4*)sm;              // [1024] : 128 rows x 8 blks swizzled
    uint4* Ws = (uint4*)(sm + 16384);    // [512]

    const int tid = threadIdx.x;
    const int lane = tid & 63, w = tid >> 6;
    const int quad = lane >> 4, l15 = lane & 15;
    const int srX = tid >> 1, sbX = (tid & 1) * 4;
    const int srW = tid >> 2, sbW = (tid & 3) * 2;

    f32x4 acc[2][4] = {};

    for (int k0 = 0; k0 < 768; k0 += 64) {
        __syncthreads();
        #pragma unroll
        for (int c = 0; c < 4; ++c) {
            const int blk = sbX + c;
            Xs[srX * 8 + (blk ^ (srX & 7))] = *(const uint4*)(p.xb + (r0 + srX) * 768 + k0 + blk * 8);
        }
        #pragma unroll
        for (int c = 0; c < 2; ++c) {
            const int blk = sbW + c;
            Ws[srW * 8 + (blk ^ (srW & 7))] = *(const uint4*)(WT + (n0 + srW) * 768 + k0 + blk * 8);
        }
        __syncthreads();
        #pragma unroll
        for (int ks = 0; ks < 2; ++ks) {
            const int a0r = 32 * w + l15, a1r = 32 * w + 16 + l15;
            const bf16x8 af0 = *(const bf16x8*)&Xs[a0r * 8 + ((quad + 4 * ks) ^ (a0r & 7))];
            const bf16x8 af1 = *(const bf16x8*)&Xs[a1r * 8 + ((quad + 4 * ks) ^ (a1r & 7))];
            #pragma unroll
            for (int ctt = 0; ctt < 4; ++ctt) {
                const int brow = 16 * ctt + l15;
                const bf16x8 bfr = *(const bf16x8*)&Ws[brow * 8 + ((quad + 4 * ks) ^ (brow & 7))];
                acc[0][ctt] = MFMA(af0, bfr, acc[0][ctt]);
                acc[1][ctt] = MFMA(af1, bfr, acc[1][ctt]);
            }
        }
    }
    #pragma unroll
    for (int half = 0; half < 2; ++half) {
        #pragma unroll
        for (int ctt = 0; ctt < 4; ++ctt) {
            const int cd = ctt * 16 + l15;
            const float bv_ = bias[n0 + cd];
            const int row0 = r0 + 32 * w + 16 * half + quad * 4;
            const int b = row0 >> 11;
            if (kind == 2) {                       // V transposed [b,g,d,s]
                const int s0 = row0 & 2047;
                unsigned hh[4];
                #pragma unroll
                for (int reg = 0; reg < 4; ++reg) hh[reg] = f2bf(acc[half][ctt][reg] + bv_);
                uint2 pkv; pkv.x = hh[0] | (hh[1] << 16); pkv.y = hh[2] | (hh[3] << 16);
                *(uint2*)(p.Vtb + ((b * 4 + head) * 64 + cd) * 2048 + s0) = pkv;
            } else {
                #pragma unroll
                for (int reg = 0; reg < 4; ++reg) {
                    const int row = row0 + reg;
                    const int s = row & 2047;
                    const ushort_t hv = f2bf(acc[half][ctt][reg] + bv_);
                    if (kind == 0) p.Qb[((b * 12 + head) * 2048 + s) * 64 + cd] = hv;
                    else           p.Kb[((b * 4 + head) * 2048 + s) * 64 + cd] = hv;
                }
            }
        }
    }
}

// ---------------------------------------------------------------------------
// P1.5: suffix sums of V rows, 64-key tile granularity, fp32. 8 jobs.
__device__ __forceinline__ void vsuffix_job(int bg, const Params& p, uint8_t* sm) {
    float (*ts)[64] = (float(*)[64])sm;
    const int tid = threadIdx.x;
    const int d = tid & 63, part = tid >> 6;
    const ushort_t* base = p.Vtb + (bg * 64 + d) * 2048;
    for (int t = part * 8; t < part * 8 + 8; ++t) {
        float sum = 0.f;
        #pragma unroll
        for (int j8 = 0; j8 < 8; ++j8) {
            const uint4 v = *(const uint4*)(base + t * 64 + j8 * 8);
            sum += bflo(v.x) + bfhi(v.x) + bflo(v.y) + bfhi(v.y)
                 + bflo(v.z) + bfhi(v.z) + bflo(v.w) + bfhi(v.w);
        }
        ts[t][d] = sum;
    }
    __syncthreads();
    if (tid < 64) {
        float acc = 0.f;
        p.Vsuf[(bg * 33 + 32) * 64 + tid] = 0.f;
        for (int t = 31; t >= 0; --t) {
            acc += ts[t][tid];
            p.Vsuf[(bg * 33 + t) * 64 + tid] = acc;
        }
    }
}

// ---------------------------------------------------------------------------
// P2: attention, triangular (r5 body). Job ja: qt = 31 - ja/24 (desc work).
__device__ __forceinline__ void attn_job(int ja, const Params& p, uint8_t* sm) {
    const int qt = 31 - ja / 24;
    const int hb = ja % 24, h = hb % 12, b = hb / 12;
    const int g = h / 3;
    const int bg = b * 4 + g;
    const int q0 = qt * 64;
    const int tid = threadIdx.x;
    const int lane = tid & 63, w = tid >> 6;
    const int quad = lane >> 4, l15 = lane & 15;

    uint4* K_l = (uint4*)sm;                     // [512] [key][blk^(key&7)]
    uint4* V_l = (uint4*)(sm + 8192);            // [512] [d][blk^(d&7)]
    ushort_t* P_l = (ushort_t*)(sm + 16384);     // [64*72] wave-private strips

    const ushort_t* Qp = p.Qb + ((b * 12 + h) * 2048 + q0 + 16 * w + l15) * 64;
    const bf16x8 qf0 = *(const bf16x8*)(Qp + quad * 8);
    const bf16x8 qf1 = *(const bf16x8*)(Qp + 32 + quad * 8);

    const ushort_t* Kp = p.Kb + bg * 2048 * 64;
    const ushort_t* Vp = p.Vtb + bg * 64 * 2048;

    f32x4 o[4] = {{0,0,0,0},{0,0,0,0},{0,0,0,0},{0,0,0,0}};
    float lsum = 0.f;

    const int sr = tid >> 2, sb = (tid & 3) * 2;
    const int thr = 16 * w + l15;
    ushort_t* Prow = P_l + (16 * w + l15) * 72;

    for (int k0 = 0; k0 <= q0; k0 += 64) {
        __syncthreads();
        #pragma unroll
        for (int c = 0; c < 2; ++c) {
            const int blk = sb + c;
            K_l[sr * 8 + (blk ^ (sr & 7))] = *(const uint4*)(Kp + (k0 + sr) * 64 + blk * 8);
            V_l[sr * 8 + (blk ^ (sr & 7))] = *(const uint4*)(Vp + sr * 2048 + k0 + blk * 8);
        }
        __syncthreads();
        // S^T = K Q^T: col=q=l15, row=key=quad*4+reg
        if (k0 < q0) {                                // fully unmasked fast path
            #pragma unroll
            for (int ctt = 0; ctt < 4; ++ctt) {
                const int key = ctt * 16 + l15;
                f32x4 s = {0, 0, 0, 0};
                s = MFMA(*(const bf16x8*)&K_l[key * 8 + ((quad + 0) ^ (key & 7))], qf0, s);
                s = MFMA(*(const bf16x8*)&K_l[key * 8 + ((quad + 4) ^ (key & 7))], qf1, s);
                const float e0 = __expf(s[0] * 0.125f), e1 = __expf(s[1] * 0.125f);
                const float e2 = __expf(s[2] * 0.125f), e3 = __expf(s[3] * 0.125f);
                lsum += (e0 + e1) + (e2 + e3);
                uint2 pw; pw.x = pk2(e0, e1); pw.y = pk2(e2, e3);
                *(uint2*)(Prow + ctt * 16 + quad * 4) = pw;
            }
        } else {                                      // diagonal tile: mask path
            #pragma unroll
            for (int ctt = 0; ctt < 4; ++ctt) {
                const int key = ctt * 16 + l15;
                f32x4 s = {0, 0, 0, 0};
                s = MFMA(*(const bf16x8*)&K_l[key * 8 + ((quad + 0) ^ (key & 7))], qf0, s);
                s = MFMA(*(const bf16x8*)&K_l[key * 8 + ((quad + 4) ^ (key & 7))], qf1, s);
                const int base = ctt * 16 + quad * 4;
                float e[4];
                #pragma unroll
                for (int reg = 0; reg < 4; ++reg) {
                    const float sv = (base + reg <= thr) ? s[reg] * 0.125f : -1e-9f;
                    e[reg] = __expf(sv);              // expf(-1e-9f) == 1.0f
                    lsum += e[reg];
                }
                uint2 pw; pw.x = pk2(e[0], e[1]); pw.y = pk2(e[2], e[3]);
                *(uint2*)(Prow + ctt * 16 + quad * 4) = pw;
            }
        }
        // O += P V
        const bf16x8 pf0 = *(const bf16x8*)(Prow + quad * 8);
        const bf16x8 pf1 = *(const bf16x8*)(Prow + 32 + quad * 8);
        #pragma unroll
        for (int ctt = 0; ctt < 4; ++ctt) {
            const int d = ctt * 16 + l15;
            o[ctt] = MFMA(pf0, *(const bf16x8*)&V_l[d * 8 + ((quad + 0) ^ (d & 7))], o[ctt]);
            o[ctt] = MFMA(pf1, *(const bf16x8*)&V_l[d * 8 + ((quad + 4) ^ (d & 7))], o[ctt]);
        }
    }
    // denominator across quads + 1.0 per future key
    float ls = lsum;
    ls += __shfl_xor(ls, 16); ls += __shfl_xor(ls, 32);
    const float invv = 1.f / (ls + (float)(1984 - q0));
    float inv_r[4];
    #pragma unroll
    for (int reg = 0; reg < 4; ++reg) inv_r[reg] = __shfl(invv, quad * 4 + reg);
    const float* vsp = p.Vsuf + (bg * 33 + qt + 1) * 64;
    const int t0 = q0 + 16 * w + quad * 4;
    #pragma unroll
    for (int ctt = 0; ctt < 4; ++ctt) {
        const int d = ctt * 16 + l15;
        const float vs = vsp[d];
        unsigned hh[4], hl[4];
        #pragma unroll
        for (int reg = 0; reg < 4; ++reg) {
            const float val = (o[ctt][reg] + vs) * inv_r[reg];
            const ushort_t hi = f2bf(val);
            union { unsigned u; float f; } vv; vv.u = (unsigned)hi << 16;
            hh[reg] = hi;
            hl[reg] = f2bf(val - vv.f);
        }
        const int idx = (b * 768 + h * 64 + d) * 2048 + t0;
        uint2 ph, pl;
        ph.x = hh[0] | (hh[1] << 16); ph.y = hh[2] | (hh[3] << 16);
        pl.x = hl[0] | (hl[1] << 16); pl.y = hl[2] | (hl[3] << 16);
        *(uint2*)(p.aT_hi + idx) = ph;
        *(uint2*)(p.aT_lo + idx) = pl;
    }
}

// ---------------------------------------------------------------------------
// P3: output projection, 64-row tiles (r3 body). 768 jobs (12 ct x 64 rt).
__device__ __forceinline__ void out_job(int jo, const Params& p, uint8_t* sm) {
    const int ct = jo / 64, rt = jo % 64;
    const int r0 = rt * 64, c0 = ct * 64;
    uint4* Ah = (uint4*)sm;
    uint4* Al = (uint4*)(sm + 8192);
    uint4* Ws = (uint4*)(sm + 16384);
    const int tid = threadIdx.x;
    const int lane = tid & 63, w = tid >> 6;
    const int quad = lane >> 4, l15 = lane & 15;
    const int sr = tid >> 2, sb = (tid & 3) * 2;

    f32x4 acc[4] = {{0,0,0,0},{0,0,0,0},{0,0,0,0},{0,0,0,0}};

    for (int k0 = 0; k0 < 768; k0 += 64) {
        __syncthreads();
        #pragma unroll
        for (int c = 0; c < 2; ++c) {
            const int blk = sb + c;
            const int slot = sr * 8 + (blk ^ (sr & 7));
            Ah[slot] = *(const uint4*)(p.aT_hi + (r0 + sr) * 768 + k0 + blk * 8);
            Al[slot] = *(const uint4*)(p.aT_lo + (r0 + sr) * 768 + k0 + blk * 8);
            Ws[slot] = *(const uint4*)(p.WoT + (c0 + sr) * 768 + k0 + blk * 8);
        }
        __syncthreads();
        #pragma unroll
        for (int ks = 0; ks < 2; ++ks) {
            const int arow = 16 * w + l15;
            const int aslot = arow * 8 + ((quad + 4 * ks) ^ (arow & 7));
            const bf16x8 ah = *(const bf16x8*)&Ah[aslot];
            const bf16x8 al = *(const bf16x8*)&Al[aslot];
            #pragma unroll
            for (int ctt = 0; ctt < 4; ++ctt) {
                const int brow = 16 * ctt + l15;
                const bf16x8 bfr = *(const bf16x8*)&Ws[brow * 8 + ((quad + 4 * ks) ^ (brow & 7))];
                acc[ctt] = MFMA(ah, bfr, acc[ctt]);
                acc[ctt] = MFMA(al, bfr, acc[ctt]);
            }
        }
    }
    #pragma unroll
    for (int ctt = 0; ctt < 4; ++ctt) {
        const int cd = c0 + ctt * 16 + l15;
        const float bo_v = p.bo[cd];
        #pragma unroll
        for (int reg = 0; reg < 4; ++reg) {
            const int row = r0 + 16 * w + quad * 4 + reg;
            p.out[row * 768 + cd] = acc[ctt][reg] + bo_v;
        }
    }
}

// ---------------------------------------------------------------------------
// The fused cooperative kernel. Grid MUST be 512 x 256.
__global__ __launch_bounds__(256, 2) void fused_kernel(Params p) {
    __shared__ __align__(16) uint8_t sm[25600];
    cg::grid_group grid = cg::this_grid();
    const int bid = blockIdx.x;

    // P0: prep (448 jobs: 64 x-cast + 384 weight-transpose)
    if (bid < 64)       prep_x_job(bid, p);
    else if (bid < 448) prep_w_job(bid - 64, p, sm);
    grid.sync();

    // P1: qkv (640 jobs)
    for (int j = bid; j < 640; j += 512) qkv_job(j, p, sm);
    grid.sync();

    // P1.5: vsuffix (8 jobs)
    if (bid < 8) vsuffix_job(bid, p, sm);
    grid.sync();

    // P2: attention, snake-balanced: bin b gets job b, and (for b>=256) job 1023-b.
    attn_job(bid, p, sm);
    if (bid >= 256) attn_job(1023 - bid, p, sm);
    grid.sync();

    // P3: out_proj (768 jobs)
    for (int j = bid; j < 768; j += 512) out_job(j, p, sm);
}

// ---------------------------------------------------------------------------
extern "C" void kernel_launch(void* const* d_in, const int* in_sizes, int n_in,
                              void* d_out, int out_size, void* d_ws, size_t ws_size,
                              hipStream_t stream) {
    uint8_t* wsb = (uint8_t*)d_ws;
    Params prm;
    prm.x  = (const float*)d_in[0];
    // d_in[1] = masks: ignored (deterministic tril; MASK_FILL applied analytically)
    prm.Wq = (const float*)d_in[2];
    prm.bq = (const float*)d_in[3];
    prm.Wk = (const float*)d_in[4];
    prm.bk = (const float*)d_in[5];
    prm.Wv = (const float*)d_in[6];
    prm.bv = (const float*)d_in[7];
    prm.Wo = (const float*)d_in[8];
    prm.bo = (const float*)d_in[9];
    prm.out = (float*)d_out;
    prm.xb    = (ushort_t*)(wsb);              // 6,291,456 B
    prm.WqT   = (ushort_t*)(wsb + 6291456);    // 1,179,648
    prm.WkT   = (ushort_t*)(wsb + 7471104);    //   393,216
    prm.WvT   = (ushort_t*)(wsb + 7864320);    //   393,216
    prm.WoT   = (ushort_t*)(wsb + 8257536);    // 1,179,648
    prm.Qb    = (ushort_t*)(wsb + 9437184);    // 6,291,456
    prm.Kb    = (ushort_t*)(wsb + 15728640);   // 2,097,152
    prm.Vtb   = (ushort_t*)(wsb + 17825792);   // 2,097,152
    prm.Vsuf  = (float*)   (wsb + 19922944);   //    67,584
    prm.aT_hi = (ushort_t*)(wsb + 19990528);   // 6,291,456
    prm.aT_lo = (ushort_t*)(wsb + 26281984);   // 6,291,456 (total ~32.6 MB)

    void* kargs[] = { (void*)&prm };
    hipLaunchCooperativeKernel((const void*)fused_kernel, dim3(512), dim3(256),
                               kargs, 0, stream);
}

// Round 8
// 292.528 us; speedup vs baseline: 1.5809x; 1.5809x over previous
//
#include <hip/hip_runtime.h>
#include <hip/hip_bf16.h>
#include <stdint.h>

// GroupQuerySelfAttention: B=2, S=2048, D=768, NH=12, GH=4, HD=64, REP=3
// SCALE=0.125, MASK_FILL=-1e-9 => masked weight = expf(-1e-9f) == 1.0f.
// Inputs fp32, output fp32 (established r1/r2).
//
// R8 = r5 pipeline (r7 proved grid.sync >> launch gaps; r6 proved LDS staging
// beats direct-global frags) with:
//   - attn: double-buffered K/V LDS, ONE barrier/iter, reg-prefetch 2 tiles ahead
//   - qkv/out_proj: 64-row tiles (more blocks/CU) + reg-prefetch next k-tile
//   - prep_x + prep_w fused into one launch (independent jobs)
//
// MFMA 16x16x32_bf16 layouts (HW-verified):
//   A[m=lane&15][k=quad*8+j]  B[n=lane&15][k=quad*8+j]  C col=lane&15,row=quad*4+reg

typedef unsigned short ushort_t;
typedef short bf16x8 __attribute__((ext_vector_type(8)));
typedef float f32x4 __attribute__((ext_vector_type(4)));

#define MFMA(a, b, c) __builtin_amdgcn_mfma_f32_16x16x32_bf16((a), (b), (c), 0, 0, 0)

__device__ __forceinline__ ushort_t f2bf(float f) {   // RNE fp32->bf16 (finite)
    union { float f; unsigned u; } v; v.f = f;
    const unsigned r = v.u + 0x7FFFu + ((v.u >> 16) & 1u);
    return (ushort_t)(r >> 16);
}
__device__ __forceinline__ unsigned pk2(float a, float b) {  // packed RNE pair
    __hip_bfloat162 h = __float22bfloat162_rn(make_float2(a, b));
    unsigned u; __builtin_memcpy(&u, &h, 4); return u;
}
__device__ __forceinline__ float bflo(unsigned u) {
    union { unsigned u; float f; } v; v.u = u << 16; return v.f;
}
__device__ __forceinline__ float bfhi(unsigned u) {
    union { unsigned u; float f; } v; v.u = u & 0xFFFF0000u; return v.f;
}

// ---------------------------------------------------------------------------
// Fused prep: blocks 0..3071 cast x fp32->bf16; blocks 3072..3455 transpose+
// cast one 64x64 weight tile ([768 k][N n] fp32 -> [N n][768 k] bf16).
__global__ __launch_bounds__(256) void prep_kernel(
    const float* __restrict__ x,
    const float* __restrict__ Wq, const float* __restrict__ Wk,
    const float* __restrict__ Wv, const float* __restrict__ Wo,
    ushort_t* __restrict__ xb,
    ushort_t* __restrict__ WqT, ushort_t* __restrict__ WkT,
    ushort_t* __restrict__ WvT, ushort_t* __restrict__ WoT) {
    __shared__ float Ts[64][65];
    const int bid = blockIdx.x;
    const int tid = threadIdx.x;
    if (bid < 3072) {
        const int i = (bid * 256 + tid) * 4;
        const float4 v = *(const float4*)(x + i);
        uint2 p; p.x = pk2(v.x, v.y); p.y = pk2(v.z, v.w);
        *(uint2*)(xb + i) = p;
        return;
    }
    const int jw = bid - 3072;   // 0..383: 144 Wq, 48 Wk, 48 Wv, 144 Wo
    const float* src; ushort_t* dst; int N, kt, nt;
    if (jw < 144)      { src = Wq; dst = WqT; N = 768; kt = jw / 12;         nt = jw % 12; }
    else if (jw < 192) { src = Wk; dst = WkT; N = 256; kt = (jw - 144) / 4;  nt = (jw - 144) % 4; }
    else if (jw < 240) { src = Wv; dst = WvT; N = 256; kt = (jw - 192) / 4;  nt = (jw - 192) % 4; }
    else               { src = Wo; dst = WoT; N = 768; kt = (jw - 240) / 12; nt = (jw - 240) % 12; }
    const int k0 = kt * 64, n0 = nt * 64;

    const int r = tid >> 2, cb = (tid & 3) * 16;
    #pragma unroll
    for (int jj = 0; jj < 4; ++jj) {
        const float4 v = *(const float4*)(src + (k0 + r) * N + n0 + cb + jj * 4);
        Ts[cb + jj * 4 + 0][r] = v.x; Ts[cb + jj * 4 + 1][r] = v.y;
        Ts[cb + jj * 4 + 2][r] = v.z; Ts[cb + jj * 4 + 3][r] = v.w;
    }
    __syncthreads();
    const int n = tid >> 2, kc = (tid & 3) * 16;
    unsigned hbuf[16];
    #pragma unroll
    for (int j = 0; j < 16; ++j) hbuf[j] = f2bf(Ts[n][kc + j]);
    uint4 p0, p1;
    p0.x = hbuf[0] | (hbuf[1] << 16);   p0.y = hbuf[2] | (hbuf[3] << 16);
    p0.z = hbuf[4] | (hbuf[5] << 16);   p0.w = hbuf[6] | (hbuf[7] << 16);
    p1.x = hbuf[8] | (hbuf[9] << 16);   p1.y = hbuf[10] | (hbuf[11] << 16);
    p1.z = hbuf[12] | (hbuf[13] << 16); p1.w = hbuf[14] | (hbuf[15] << 16);
    *(uint4*)(dst + (n0 + n) * 768 + k0 + kc) = p0;
    *(uint4*)(dst + (n0 + n) * 768 + k0 + kc + 8) = p1;
}

// ---------------------------------------------------------------------------
// QKV projection, 64-row tiles + reg prefetch. grid (20 ct, 64 rt).
__global__ __launch_bounds__(256) void qkv_kernel(
    const ushort_t* __restrict__ xb,
    const ushort_t* __restrict__ WqT, const ushort_t* __restrict__ WkT,
    const ushort_t* __restrict__ WvT,
    const float* __restrict__ bq, const float* __restrict__ bk,
    const float* __restrict__ bv,
    ushort_t* __restrict__ Qb, ushort_t* __restrict__ Kb,
    ushort_t* __restrict__ Vtb) {
    const int ct = blockIdx.x, rt = blockIdx.y;
    const int r0 = rt * 64;
    const ushort_t* WT; const float* bias; int head, kind;   // 0=Q,1=K,2=V
    if (ct < 12)      { WT = WqT; bias = bq; head = ct;      kind = 0; }
    else if (ct < 16) { WT = WkT; bias = bk; head = ct - 12; kind = 1; }
    else              { WT = WvT; bias = bv; head = ct - 16; kind = 2; }
    const int n0 = head * 64;

    __shared__ uint4 Xs[512];   // [64 rows][8 blks] XOR-swizzled
    __shared__ uint4 Ws[512];

    const int tid = threadIdx.x;
    const int lane = tid & 63, w = tid >> 6;
    const int quad = lane >> 4, l15 = lane & 15;
    const int sr = tid >> 2, sb = (tid & 3) * 2;

    const ushort_t* xp = xb + (r0 + sr) * 768;
    const ushort_t* wp = WT + (n0 + sr) * 768;

    uint4 xr[2], wr[2];
    #pragma unroll
    for (int c = 0; c < 2; ++c) {
        xr[c] = *(const uint4*)(xp + (sb + c) * 8);
        wr[c] = *(const uint4*)(wp + (sb + c) * 8);
    }

    f32x4 acc[4] = {{0,0,0,0},{0,0,0,0},{0,0,0,0},{0,0,0,0}};

    for (int k0 = 0; k0 < 768; k0 += 64) {
        __syncthreads();
        #pragma unroll
        for (int c = 0; c < 2; ++c) {
            const int blk = sb + c;
            Xs[sr * 8 + (blk ^ (sr & 7))] = xr[c];
            Ws[sr * 8 + (blk ^ (sr & 7))] = wr[c];
        }
        __syncthreads();
        if (k0 + 64 < 768) {
            #pragma unroll
            for (int c = 0; c < 2; ++c) {
                xr[c] = *(const uint4*)(xp + k0 + 64 + (sb + c) * 8);
                wr[c] = *(const uint4*)(wp + k0 + 64 + (sb + c) * 8);
            }
        }
        #pragma unroll
        for (int ks = 0; ks < 2; ++ks) {
            const int arow = 16 * w + l15;
            const bf16x8 af = *(const bf16x8*)&Xs[arow * 8 + ((quad + 4 * ks) ^ (arow & 7))];
            #pragma unroll
            for (int ctt = 0; ctt < 4; ++ctt) {
                const int brow = 16 * ctt + l15;
                const bf16x8 bfr = *(const bf16x8*)&Ws[brow * 8 + ((quad + 4 * ks) ^ (brow & 7))];
                acc[ctt] = MFMA(af, bfr, acc[ctt]);
            }
        }
    }

    const int row0 = r0 + 16 * w + quad * 4;
    const int b = row0 >> 11;
    #pragma unroll
    for (int ctt = 0; ctt < 4; ++ctt) {
        const int cd = ctt * 16 + l15;
        const float bv_ = bias[n0 + cd];
        if (kind == 2) {                       // V transposed [b,g,d,s]
            const int s0 = row0 & 2047;
            unsigned hh[4];
            #pragma unroll
            for (int reg = 0; reg < 4; ++reg) hh[reg] = f2bf(acc[ctt][reg] + bv_);
            uint2 pkv; pkv.x = hh[0] | (hh[1] << 16); pkv.y = hh[2] | (hh[3] << 16);
            *(uint2*)(Vtb + ((b * 4 + head) * 64 + cd) * 2048 + s0) = pkv;
        } else {
            #pragma unroll
            for (int reg = 0; reg < 4; ++reg) {
                const int row = row0 + reg;
                const int s = row & 2047;
                const ushort_t hv = f2bf(acc[ctt][reg] + bv_);
                if (kind == 0) Qb[((b * 12 + head) * 2048 + s) * 64 + cd] = hv;
                else           Kb[((b * 4 + head) * 2048 + s) * 64 + cd] = hv;
            }
        }
    }
}

// ---------------------------------------------------------------------------
// Suffix sums of V rows at 64-key tile granularity, fp32. grid(8).
__global__ __launch_bounds__(256) void vsuffix_kernel(
    const ushort_t* __restrict__ Vtb, float* __restrict__ Vsuf) {
    const int bg = blockIdx.x;
    const int tid = threadIdx.x;
    const int d = tid & 63, part = tid >> 6;
    __shared__ float ts[32][64];
    const ushort_t* base = Vtb + (bg * 64 + d) * 2048;
    for (int t = part * 8; t < part * 8 + 8; ++t) {
        float sum = 0.f;
        #pragma unroll
        for (int j8 = 0; j8 < 8; ++j8) {
            const uint4 v = *(const uint4*)(base + t * 64 + j8 * 8);
            sum += bflo(v.x) + bfhi(v.x) + bflo(v.y) + bfhi(v.y)
                 + bflo(v.z) + bfhi(v.z) + bflo(v.w) + bfhi(v.w);
        }
        ts[t][d] = sum;
    }
    __syncthreads();
    if (tid < 64) {
        float acc = 0.f;
        Vsuf[(bg * 33 + 32) * 64 + tid] = 0.f;
        for (int t = 31; t >= 0; --t) {
            acc += ts[t][tid];
            Vsuf[(bg * 33 + t) * 64 + tid] = acc;
        }
    }
}

// ---------------------------------------------------------------------------
// Attention, triangular, double-buffered K/V LDS, ONE barrier per iter.
// grid (32 qt, 12 h, 2 b); qt = 31-bx (heavy first).
__global__ __launch_bounds__(256) void attn_kernel(
    const ushort_t* __restrict__ Qb, const ushort_t* __restrict__ Kb,
    const ushort_t* __restrict__ Vtb, const float* __restrict__ Vsuf,
    ushort_t* __restrict__ aT_hi, ushort_t* __restrict__ aT_lo) {
    const int qt = 31 - blockIdx.x, h = blockIdx.y, b = blockIdx.z;
    const int g = h / 3;
    const int bg = b * 4 + g;
    const int q0 = qt * 64;
    const int tid = threadIdx.x;
    const int lane = tid & 63, w = tid >> 6;
    const int quad = lane >> 4, l15 = lane & 15;

    __shared__ uint4 K_l[2][512];                    // [buf][key][blk^(key&7)]
    __shared__ uint4 V_l[2][512];                    // [buf][d][blk^(d&7)]
    __shared__ __align__(16) ushort_t P_l[64 * 72];  // wave-private strips

    // Q fragments (B-operand: n = q = 16w + l15)
    const ushort_t* Qp = Qb + ((b * 12 + h) * 2048 + q0 + 16 * w + l15) * 64;
    const bf16x8 qf0 = *(const bf16x8*)(Qp + quad * 8);
    const bf16x8 qf1 = *(const bf16x8*)(Qp + 32 + quad * 8);

    const ushort_t* Kp = Kb + bg * 2048 * 64;
    const ushort_t* Vp = Vtb + bg * 64 * 2048;

    f32x4 o[4] = {{0,0,0,0},{0,0,0,0},{0,0,0,0},{0,0,0,0}};
    float lsum = 0.f;

    const int sr = tid >> 2, sb = (tid & 3) * 2;
    const int thr = 16 * w + l15;
    ushort_t* Prow = P_l + (16 * w + l15) * 72;
    const int slot0 = sr * 8 + (sb ^ (sr & 7));
    const int slot1 = sr * 8 + ((sb + 1) ^ (sr & 7));

    // prologue: tile 0 -> regs -> buf0; tile 1 -> regs
    uint4 kr0, kr1, vr0, vr1;
    kr0 = *(const uint4*)(Kp + sr * 64 + sb * 8);
    kr1 = *(const uint4*)(Kp + sr * 64 + (sb + 1) * 8);
    vr0 = *(const uint4*)(Vp + sr * 2048 + sb * 8);
    vr1 = *(const uint4*)(Vp + sr * 2048 + (sb + 1) * 8);
    K_l[0][slot0] = kr0; K_l[0][slot1] = kr1;
    V_l[0][slot0] = vr0; V_l[0][slot1] = vr1;
    if (qt >= 1) {
        kr0 = *(const uint4*)(Kp + (64 + sr) * 64 + sb * 8);
        kr1 = *(const uint4*)(Kp + (64 + sr) * 64 + (sb + 1) * 8);
        vr0 = *(const uint4*)(Vp + sr * 2048 + 64 + sb * 8);
        vr1 = *(const uint4*)(Vp + sr * 2048 + 64 + (sb + 1) * 8);
    }
    __syncthreads();

    for (int i = 0; i <= qt; ++i) {
        const int cur = i & 1;
        if (i < qt) {
            // store tile i+1 (in regs) to the other buffer
            K_l[cur ^ 1][slot0] = kr0; K_l[cur ^ 1][slot1] = kr1;
            V_l[cur ^ 1][slot0] = vr0; V_l[cur ^ 1][slot1] = vr1;
            if (i + 1 < qt) {           // prefetch tile i+2
                const int kt = (i + 2) * 64;
                kr0 = *(const uint4*)(Kp + (kt + sr) * 64 + sb * 8);
                kr1 = *(const uint4*)(Kp + (kt + sr) * 64 + (sb + 1) * 8);
                vr0 = *(const uint4*)(Vp + sr * 2048 + kt + sb * 8);
                vr1 = *(const uint4*)(Vp + sr * 2048 + kt + (sb + 1) * 8);
            }
        }
        const uint4* Kc = K_l[cur];
        const uint4* Vc = V_l[cur];
        // S^T = K Q^T: col=q=l15, row=key=quad*4+reg
        if (i < qt) {                                 // fully unmasked fast path
            #pragma unroll
            for (int ctt = 0; ctt < 4; ++ctt) {
                const int key = ctt * 16 + l15;
                f32x4 s = {0, 0, 0, 0};
                s = MFMA(*(const bf16x8*)&Kc[key * 8 + ((quad + 0) ^ (key & 7))], qf0, s);
                s = MFMA(*(const bf16x8*)&Kc[key * 8 + ((quad + 4) ^ (key & 7))], qf1, s);
                const float e0 = __expf(s[0] * 0.125f), e1 = __expf(s[1] * 0.125f);
                const float e2 = __expf(s[2] * 0.125f), e3 = __expf(s[3] * 0.125f);
                lsum += (e0 + e1) + (e2 + e3);
                uint2 pw; pw.x = pk2(e0, e1); pw.y = pk2(e2, e3);
                *(uint2*)(Prow + ctt * 16 + quad * 4) = pw;
            }
        } else {                                      // diagonal tile: mask path
            #pragma unroll
            for (int ctt = 0; ctt < 4; ++ctt) {
                const int key = ctt * 16 + l15;
                f32x4 s = {0, 0, 0, 0};
                s = MFMA(*(const bf16x8*)&Kc[key * 8 + ((quad + 0) ^ (key & 7))], qf0, s);
                s = MFMA(*(const bf16x8*)&Kc[key * 8 + ((quad + 4) ^ (key & 7))], qf1, s);
                const int base = ctt * 16 + quad * 4;
                float e[4];
                #pragma unroll
                for (int reg = 0; reg < 4; ++reg) {
                    const float sv = (base + reg <= thr) ? s[reg] * 0.125f : -1e-9f;
                    e[reg] = __expf(sv);              // expf(-1e-9f) == 1.0f
                    lsum += e[reg];
                }
                uint2 pw; pw.x = pk2(e[0], e[1]); pw.y = pk2(e[2], e[3]);
                *(uint2*)(Prow + ctt * 16 + quad * 4) = pw;
            }
        }
        // O += P V
        const bf16x8 pf0 = *(const bf16x8*)(Prow + quad * 8);
        const bf16x8 pf1 = *(const bf16x8*)(Prow + 32 + quad * 8);
        #pragma unroll
        for (int ctt = 0; ctt < 4; ++ctt) {
            const int d = ctt * 16 + l15;
            o[ctt] = MFMA(pf0, *(const bf16x8*)&Vc[d * 8 + ((quad + 0) ^ (d & 7))], o[ctt]);
            o[ctt] = MFMA(pf1, *(const bf16x8*)&Vc[d * 8 + ((quad + 4) ^ (d & 7))], o[ctt]);
        }
        __syncthreads();
    }
    // denominator across quads + 1.0 per future key
    float ls = lsum;
    ls += __shfl_xor(ls, 16); ls += __shfl_xor(ls, 32);
    const float invv = 1.f / (ls + (float)(1984 - q0));
    float inv_r[4];
    #pragma unroll
    for (int reg = 0; reg < 4; ++reg) inv_r[reg] = __shfl(invv, quad * 4 + reg);
    const float* vsp = Vsuf + (bg * 33 + qt + 1) * 64;
    const int t0 = q0 + 16 * w + quad * 4;
    #pragma unroll
    for (int ctt = 0; ctt < 4; ++ctt) {
        const int d = ctt * 16 + l15;
        const float vs = vsp[d];
        unsigned hh[4], hl[4];
        #pragma unroll
        for (int reg = 0; reg < 4; ++reg) {
            const float val = (o[ctt][reg] + vs) * inv_r[reg];
            const ushort_t hi = f2bf(val);
            union { unsigned u; float f; } vv; vv.u = (unsigned)hi << 16;
            hh[reg] = hi;
            hl[reg] = f2bf(val - vv.f);
        }
        const int idx = (b * 768 + h * 64 + d) * 2048 + t0;
        uint2 ph, pl;
        ph.x = hh[0] | (hh[1] << 16); ph.y = hh[2] | (hh[3] << 16);
        pl.x = hl[0] | (hl[1] << 16); pl.y = hl[2] | (hl[3] << 16);
        *(uint2*)(aT_hi + idx) = ph;
        *(uint2*)(aT_lo + idx) = pl;
    }
}

// ---------------------------------------------------------------------------
// Output projection, 64-row tiles + reg prefetch: (aT_hi+aT_lo)@WoT + bo.
// grid (12 ct, 64 rt).
__global__ __launch_bounds__(256) void out_proj_kernel(
    const ushort_t* __restrict__ aT_hi, const ushort_t* __restrict__ aT_lo,
    const ushort_t* __restrict__ WoT, const float* __restrict__ bo,
    float* __restrict__ out) {
    const int ct = blockIdx.x, rt = blockIdx.y;
    const int r0 = rt * 64, c0 = ct * 64;
    __shared__ uint4 Ah[512];
    __shared__ uint4 Al[512];
    __shared__ uint4 Ws[512];
    const int tid = threadIdx.x;
    const int lane = tid & 63, w = tid >> 6;
    const int quad = lane >> 4, l15 = lane & 15;
    const int sr = tid >> 2, sb = (tid & 3) * 2;

    const ushort_t* ahp = aT_hi + (r0 + sr) * 768;
    const ushort_t* alp = aT_lo + (r0 + sr) * 768;
    const ushort_t* wop = WoT + (c0 + sr) * 768;

    uint4 ahr[2], alr[2], wr[2];
    #pragma unroll
    for (int c = 0; c < 2; ++c) {
        ahr[c] = *(const uint4*)(ahp + (sb + c) * 8);
        alr[c] = *(const uint4*)(alp + (sb + c) * 8);
        wr[c]  = *(const uint4*)(wop + (sb + c) * 8);
    }

    f32x4 acc[4] = {{0,0,0,0},{0,0,0,0},{0,0,0,0},{0,0,0,0}};

    for (int k0 = 0; k0 < 768; k0 += 64) {
        __syncthreads();
        #pragma unroll
        for (int c = 0; c < 2; ++c) {
            const int slot = sr * 8 + ((sb + c) ^ (sr & 7));
            Ah[slot] = ahr[c];
            Al[slot] = alr[c];
            Ws[slot] = wr[c];
        }
        __syncthreads();
        if (k0 + 64 < 768) {
            #pragma unroll
            for (int c = 0; c < 2; ++c) {
                ahr[c] = *(const uint4*)(ahp + k0 + 64 + (sb + c) * 8);
                alr[c] = *(const uint4*)(alp + k0 + 64 + (sb + c) * 8);
                wr[c]  = *(const uint4*)(wop + k0 + 64 + (sb + c) * 8);
            }
        }
        #pragma unroll
        for (int ks = 0; ks < 2; ++ks) {
            const int arow = 16 * w + l15;
            const int aslot = arow * 8 + ((quad + 4 * ks) ^ (arow & 7));
            const bf16x8 ah = *(const bf16x8*)&Ah[aslot];
            const bf16x8 al = *(const bf16x8*)&Al[aslot];
            #pragma unroll
            for (int ctt = 0; ctt < 4; ++ctt) {
                const int brow = 16 * ctt + l15;
                const bf16x8 bfr = *(const bf16x8*)&Ws[brow * 8 + ((quad + 4 * ks) ^ (brow & 7))];
                acc[ctt] = MFMA(ah, bfr, acc[ctt]);
                acc[ctt] = MFMA(al, bfr, acc[ctt]);
            }
        }
    }
    #pragma unroll
    for (int ctt = 0; ctt < 4; ++ctt) {
        const int cd = c0 + ctt * 16 + l15;
        const float bo_v = bo[cd];
        #pragma unroll
        for (int reg = 0; reg < 4; ++reg) {
            const int row = r0 + 16 * w + quad * 4 + reg;
            out[row * 768 + cd] = acc[ctt][reg] + bo_v;
        }
    }
}

// ---------------------------------------------------------------------------
extern "C" void kernel_launch(void* const* d_in, const int* in_sizes, int n_in,
                              void* d_out, int out_size, void* d_ws, size_t ws_size,
                              hipStream_t stream) {
    const float* x  = (const float*)d_in[0];
    // d_in[1] = masks: ignored (deterministic tril; MASK_FILL applied analytically)
    const float* Wq = (const float*)d_in[2];
    const float* bq = (const float*)d_in[3];
    const float* Wk = (const float*)d_in[4];
    const float* bk = (const float*)d_in[5];
    const float* Wv = (const float*)d_in[6];
    const float* bv = (const float*)d_in[7];
    const float* Wo = (const float*)d_in[8];
    const float* bo = (const float*)d_in[9];
    float* out = (float*)d_out;

    uint8_t* wsb = (uint8_t*)d_ws;
    ushort_t* xb    = (ushort_t*)(wsb);              // 6,291,456 B
    ushort_t* WqT   = (ushort_t*)(wsb + 6291456);    // 1,179,648
    ushort_t* WkT   = (ushort_t*)(wsb + 7471104);    //   393,216
    ushort_t* WvT   = (ushort_t*)(wsb + 7864320);    //   393,216
    ushort_t* WoT   = (ushort_t*)(wsb + 8257536);    // 1,179,648
    ushort_t* Qb    = (ushort_t*)(wsb + 9437184);    // 6,291,456
    ushort_t* Kb    = (ushort_t*)(wsb + 15728640);   // 2,097,152
    ushort_t* Vtb   = (ushort_t*)(wsb + 17825792);   // 2,097,152
    float*    Vsuf  = (float*)   (wsb + 19922944);   //    67,584
    ushort_t* aT_hi = (ushort_t*)(wsb + 19990528);   // 6,291,456
    ushort_t* aT_lo = (ushort_t*)(wsb + 26281984);   // 6,291,456 (total ~32.6 MB)

    prep_kernel<<<3456, 256, 0, stream>>>(x, Wq, Wk, Wv, Wo, xb, WqT, WkT, WvT, WoT);
    qkv_kernel<<<dim3(20, 64), 256, 0, stream>>>(xb, WqT, WkT, WvT, bq, bk, bv, Qb, Kb, Vtb);
    vsuffix_kernel<<<8, 256, 0, stream>>>(Vtb, Vsuf);
    attn_kernel<<<dim3(32, 12, 2), 256, 0, stream>>>(Qb, Kb, Vtb, Vsuf, aT_hi, aT_lo);
    out_proj_kernel<<<dim3(12, 64), 256, 0, stream>>>(aT_hi, aT_lo, WoT, bo, out);
}